// Round 9
// baseline (153.244 us; speedup 1.0000x reference)
//
#include <hip/hip_runtime.h>

#define TL 2048
#define NHEAD 8
#define NLOC 4
#define L2E 1.44269504f
#define PSTRIDE 4352   // f32 per partial: 4096 (32dp x 128q u32 bf16x2) + 128 m + 128 l

typedef __attribute__((ext_vector_type(4))) float f32x4;
typedef __attribute__((ext_vector_type(16))) float f32x16;
typedef __attribute__((ext_vector_type(8))) __bf16 bf16x8;
typedef __attribute__((ext_vector_type(8))) unsigned short u16x8;
typedef __attribute__((ext_vector_type(4))) unsigned int u32x4;

static __device__ __forceinline__ unsigned short f2bf(float f) {
    unsigned u = __float_as_uint(f);
    u = (u + 0x7FFFu + ((u >> 16) & 1u)) >> 16;
    return (unsigned short)u;
}
static __device__ __forceinline__ unsigned int cvtpk(float a, float b) {
    unsigned int w;
    asm("v_cvt_pk_bf16_f32 %0, %1, %2" : "=v"(w) : "v"(a), "v"(b));
    return w;
}
static __device__ __forceinline__ void gl_lds16(const void* g, void* l) {
    __builtin_amdgcn_global_load_lds(
        (const __attribute__((address_space(1))) void*)g,
        (__attribute__((address_space(3))) void*)l, 16, 0, 0);
}

// rel_scores[h', r] = dot(rel_pos_w[r, h'*64:+64], mlp_w[h']) * log2e -> f32
__global__ __launch_bounds__(256) void relscore_kernel(
    const float* __restrict__ rel_pos_w, const float* __restrict__ mlp_w,
    float* __restrict__ rel_sf) {
    int r = blockIdx.x;      // 0..4094
    int t = threadIdx.x;
    int w = t >> 6, lane = t & 63;
    float v = rel_pos_w[r * 256 + t] * mlp_w[t];
#pragma unroll
    for (int off = 32; off; off >>= 1) v += __shfl_xor(v, off);
    if (lane == 0) rel_sf[w * 4096 + r] = v * L2E;
}

// Per (bh, kt): K tile -> bf16 swizzled [64 k][8 d-chunks], V tile -> bf16
// transposed+swizzled [64 d][8 k-chunks]; chunk c of row r stored at c^(r&7).
// Fused: v_term f32 (local heads).
__global__ __launch_bounds__(256) void preconv_kernel(
    const float* __restrict__ key, const float* __restrict__ value,
    const float* __restrict__ mlp_w,
    unsigned short* __restrict__ Kb, unsigned short* __restrict__ Vtb,
    float* __restrict__ vtbf) {
    __shared__ float Vf[64][66];
    int blk = blockIdx.x;            // bh*32 + kt
    int t = threadIdx.x;
    int bh = blk >> 5, kt = blk & 31;
    int h = bh & 7, b = bh >> 3;
    size_t src = (size_t)blk * 4096;
    size_t dst = (size_t)blk * 4096;

#pragma unroll
    for (int i = 0; i < 2; ++i) {
        int ch = t + i * 256;
        int row = ch >> 3, c = ch & 7;
        const float* kp = key + src + row * 64 + c * 8;
        f32x4 a = *(const f32x4*)kp;
        f32x4 bb = *(const f32x4*)(kp + 4);
        u16x8 o;
#pragma unroll
        for (int j = 0; j < 4; ++j) { o[j] = f2bf(a[j]); o[4 + j] = f2bf(bb[j]); }
        *(u16x8*)&Kb[dst + row * 64 + ((c ^ (row & 7)) << 3)] = o;
    }
    {
        int row = t >> 2, q4 = t & 3;
        const float* vp = value + src + row * 64 + q4 * 16;
#pragma unroll
        for (int j = 0; j < 4; ++j)
            *(f32x4*)&Vf[row][q4 * 16 + j * 4] = *(const f32x4*)(vp + j * 4);
    }
    __syncthreads();
#pragma unroll
    for (int i = 0; i < 2; ++i) {
        int ch = t + i * 256;
        int dr = ch >> 3, c = ch & 7;
        u16x8 o;
#pragma unroll
        for (int j = 0; j < 8; ++j) o[j] = f2bf(Vf[c * 8 + j][dr]);
        *(u16x8*)&Vtb[dst + dr * 64 + ((c ^ (dr & 7)) << 3)] = o;
    }
    if (h >= NLOC) {
        int wave = t >> 6, lane = t & 63;
        float mw = mlp_w[(h - NLOC) * 64 + lane];
        float* vout = vtbf + (size_t)((b * NLOC + h - NLOC) * TL) + kt * 64;
#pragma unroll
        for (int i = 0; i < 16; ++i) {
            int row = wave * 16 + i;
            float v = Vf[row][lane] * mw;
#pragma unroll
            for (int off = 32; off; off >>= 1) v += __shfl_xor(v, off);
            if (lane == 0) vout[row] = v * L2E;
        }
    }
}

#define MFMA32(A, B, C) __builtin_amdgcn_mfma_f32_32x32x16_bf16(A, B, C, 0, 0, 0)

// Flash attention, 32x32 MFMA, swapped QK^T, in-register P.
// 1 block = 4 waves x 32 q = 128 q-rows of one (bh, i), k-strip of <=6 tiles.
// Merged 64-k softmax: S0/S1 live together -> one max/sum reduce per tile.
// All blocks write unnormalized partials (bf16 O^T + m + l); merge combines.
__global__ __launch_bounds__(256, 4) void attn_kernel(
    const float* __restrict__ query,
    const unsigned short* __restrict__ Kb, const unsigned short* __restrict__ Vtb,
    const float* __restrict__ rel_sf, const float* __restrict__ vtbf,
    float* __restrict__ part) {

    __shared__ __align__(16) unsigned char smem[35328];
    unsigned short* Ks0 = (unsigned short*)smem;            // [2][4096] u16
    unsigned short* Vt0 = (unsigned short*)(smem + 16384);  // [2][4096] u16
    float* relw  = (float*)(smem + 32768);                  // [512] f32 window
    float* biasf = (float*)(smem + 34816);                  // [2][64] f32

    int bid = blockIdx.x;          // 1632 = 51 sids x 32 bh, heavy sids first
    int bh = bid & 31;
    int sid = bid >> 5;
    // sid -> (i, s): i = 15..0, ns(i) = ceil((2i+2)/6) strips each
    int i = 0, s = 0, acc = 0;
#pragma unroll
    for (int ii = 15; ii >= 0; --ii) {
        int ns = (2 * ii + 7) / 6;
        if (sid >= acc && sid < acc + ns) { i = ii; s = sid - acc; }
        acc += ns;
    }
    int k_b = 6 * s;
    int k_e = min(6 * s + 6, 2 * i + 2);
    int q0 = i << 7;

    int h = bh & 7, b = bh >> 3;
    bool islocal = (h >= NLOC);
    int t = threadIdx.x;
    int w = t >> 6;
    int l31 = t & 31;
    int hi = (t >> 5) & 1;
    int sw = l31 & 7;
    int qrel = 32 * w + l31;
    int qglob = q0 + qrel;
    int qmaxw = q0 + 32 * w + 31;

    size_t tbase = (size_t)bh * 32 * 4096;
    const unsigned short* Ktiles = Kb + tbase;
    const unsigned short* Vtiles = Vtb + tbase;
    const float* vtpf = vtbf + (islocal ? (size_t)((b * NLOC + h - NLOC) * TL) : 0);
    int idxlo = 64 * k_b - q0 + 1920;                  // multiple of 64, >= 0
    const float* relsrc = rel_sf + (islocal ? ((h - NLOC) * 4096 + idxlo) : 0);

    // ---- prologue: stage tile k_b (async), rel window (512 f32), bias[0] ----
    gl_lds16(Ktiles + (size_t)k_b * 4096 + t * 8, Ks0 + t * 8);
    gl_lds16(Ktiles + (size_t)k_b * 4096 + 2048 + t * 8, Ks0 + 2048 + t * 8);
    gl_lds16(Vtiles + (size_t)k_b * 4096 + t * 8, Vt0 + t * 8);
    gl_lds16(Vtiles + (size_t)k_b * 4096 + 2048 + t * 8, Vt0 + 2048 + t * 8);
    if (islocal) {
        if (t < 128) *((f32x4*)relw + t) = *((const f32x4*)relsrc + t);
        if (t < 16) ((f32x4*)biasf)[t] = ((const f32x4*)(vtpf + (size_t)k_b * 64))[t];
    }

    // Q fragments (B-operand): col q = lane&31, d = 16*mq + 8*hi + e
    const float SC = 0.125f * L2E;
    bf16x8 qf[4];
    {
        const float* qsrc = query + ((size_t)bh * TL + qglob) * 64 + 8 * hi;
#pragma unroll
        for (int mq = 0; mq < 4; ++mq) {
            f32x4 a = *(const f32x4*)(qsrc + 16 * mq);
            f32x4 c = *(const f32x4*)(qsrc + 16 * mq + 4);
            u16x8 u;
#pragma unroll
            for (int j = 0; j < 4; ++j) { u[j] = f2bf(a[j] * SC); u[4 + j] = f2bf(c[j] * SC); }
            qf[mq] = __builtin_bit_cast(bf16x8, u);
        }
    }

    float m = -1e30f, lsum = 0.f;
    f32x16 O0 = {0,0,0,0,0,0,0,0,0,0,0,0,0,0,0,0};
    f32x16 O1 = {0,0,0,0,0,0,0,0,0,0,0,0,0,0,0,0};

    __syncthreads();

    int cur = 0;
    for (int kt = k_b; kt < k_e; ++kt) {
        unsigned short* Ks = Ks0 + cur * 4096;
        unsigned short* Vt = Vt0 + cur * 4096;
        const float* bias = biasf + cur * 64;

        if (kt + 1 < k_e) {
            int nb = cur ^ 1;
            gl_lds16(Ktiles + (size_t)(kt + 1) * 4096 + t * 8, Ks0 + nb * 4096 + t * 8);
            gl_lds16(Ktiles + (size_t)(kt + 1) * 4096 + 2048 + t * 8, Ks0 + nb * 4096 + 2048 + t * 8);
            gl_lds16(Vtiles + (size_t)(kt + 1) * 4096 + t * 8, Vt0 + nb * 4096 + t * 8);
            gl_lds16(Vtiles + (size_t)(kt + 1) * 4096 + 2048 + t * 8, Vt0 + nb * 4096 + 2048 + t * 8);
            if (islocal && t < 16)
                ((f32x4*)(biasf + nb * 64))[t] =
                    ((const f32x4*)(vtpf + (size_t)(kt + 1) * 64))[t];
        }

        bool active = (64 * kt <= qmaxw);           // wave-uniform
        bool maskt = (64 * kt + 63 > q0 + 32 * w);  // tile crosses diagonal
        if (active) {
            // ---- S^T = mfma(K, Q), both 32-k halves in flight ----
            f32x16 S0 = {0,0,0,0,0,0,0,0,0,0,0,0,0,0,0,0};
            f32x16 S1 = {0,0,0,0,0,0,0,0,0,0,0,0,0,0,0,0};
            __builtin_amdgcn_s_setprio(1);
#pragma unroll
            for (int mq = 0; mq < 4; ++mq) {
                int ch = ((2 * mq + hi) ^ sw) << 3;
                const bf16x8 kf0 = *(const bf16x8*)&Ks[l31 * 64 + ch];
                const bf16x8 kf1 = *(const bf16x8*)&Ks[(32 + l31) * 64 + ch];
                S0 = MFMA32(kf0, qf[mq], S0);
                S1 = MFMA32(kf1, qf[mq], S1);
            }
            __builtin_amdgcn_s_setprio(0);
            // lane: q = qglob; k = 64kt + 32*half + (r&3) + 8(r>>2) + 4hi

            if (islocal) {
                int rbase = 64 * (kt - k_b) + 4 * hi + 127 - qrel;
#pragma unroll
                for (int h2 = 0; h2 < 2; ++h2)
#pragma unroll
                    for (int g = 0; g < 4; ++g) {
                        int kk0 = 32 * h2 + 8 * g + 4 * hi;
                        f32x4 bv = *(const f32x4*)&bias[kk0];
#pragma unroll
                        for (int j = 0; j < 4; ++j) {
                            float add = bv[j] + relw[rbase + 32 * h2 + 8 * g + j];
                            if (h2) S1[4 * g + j] += add;
                            else    S0[4 * g + j] += add;
                        }
                    }
            }
            if (maskt) {
                int koff = 64 * kt + 4 * hi - qglob;
#pragma unroll
                for (int r = 0; r < 16; ++r) {
                    int kk = (r & 3) + 8 * (r >> 2);
                    if (koff + kk > 0)      S0[r] = -1e30f;
                    if (koff + 32 + kk > 0) S1[r] = -1e30f;
                }
            }
            // ---- single online softmax over all 64 k (exp2 domain) ----
            float pmax = -1e30f;
#pragma unroll
            for (int r = 0; r < 16; ++r) pmax = fmaxf(pmax, fmaxf(S0[r], S1[r]));
            pmax = fmaxf(pmax, __shfl_xor(pmax, 32));
            if (__any(pmax > m + 11.5f)) {
                float nm2 = fmaxf(m, pmax);
                float corr = exp2f(m - nm2);
                lsum *= corr;
#pragma unroll
                for (int r = 0; r < 16; ++r) { O0[r] *= corr; O1[r] *= corr; }
                m = nm2;
            }
            float ps = 0.f;
#pragma unroll
            for (int r = 0; r < 16; ++r) {
                float p0 = exp2f(S0[r] - m), p1 = exp2f(S1[r] - m);
                S0[r] = p0; S1[r] = p1; ps += p0 + p1;
            }
            ps += __shfl_xor(ps, 32);
            lsum += ps;

            // ---- P -> bf16 frags in-register (lane<->lane+32), PV ----
            __builtin_amdgcn_s_setprio(1);
#pragma unroll
            for (int g = 0; g < 4; ++g) {
                int ra = 8 * (g & 1);
                unsigned int x0, x1, y0, y1;
                if (g & 2) {
                    x0 = cvtpk(S1[ra + 0], S1[ra + 1]); x1 = cvtpk(S1[ra + 2], S1[ra + 3]);
                    y0 = cvtpk(S1[ra + 4], S1[ra + 5]); y1 = cvtpk(S1[ra + 6], S1[ra + 7]);
                } else {
                    x0 = cvtpk(S0[ra + 0], S0[ra + 1]); x1 = cvtpk(S0[ra + 2], S0[ra + 3]);
                    y0 = cvtpk(S0[ra + 4], S0[ra + 5]); y1 = cvtpk(S0[ra + 6], S0[ra + 7]);
                }
                unsigned int sx0 = __shfl_xor(x0, 32), sx1 = __shfl_xor(x1, 32);
                unsigned int sy0 = __shfl_xor(y0, 32), sy1 = __shfl_xor(y1, 32);
                u32x4 fw;
                fw[0] = hi ? sy0 : x0;
                fw[1] = hi ? sy1 : x1;
                fw[2] = hi ? y0 : sx0;
                fw[3] = hi ? y1 : sx1;
                const bf16x8 pf = __builtin_bit_cast(bf16x8, fw);
                int ch = ((2 * g + hi) ^ sw) << 3;
                const bf16x8 vf0 = *(const bf16x8*)&Vt[l31 * 64 + ch];
                const bf16x8 vf1 = *(const bf16x8*)&Vt[(32 + l31) * 64 + ch];
                O0 = MFMA32(vf0, pf, O0);
                O1 = MFMA32(vf1, pf, O1);
            }
            __builtin_amdgcn_s_setprio(0);
        }
        __syncthreads();   // next tile staged; everyone done with cur
        cur ^= 1;
    }

    // ---- partial dump: [dp 32][q 128] u32 (bf16 pair), then m, l ----
    float* pp = part + (size_t)bid * PSTRIDE;
    unsigned int* po = (unsigned int*)pp;
#pragma unroll
    for (int g = 0; g < 4; ++g) {
        unsigned int w0 = cvtpk(O0[4 * g + 0], O0[4 * g + 1]);
        unsigned int w1 = cvtpk(O0[4 * g + 2], O0[4 * g + 3]);
        unsigned int w2 = cvtpk(O1[4 * g + 0], O1[4 * g + 1]);
        unsigned int w3 = cvtpk(O1[4 * g + 2], O1[4 * g + 3]);
        int dp0 = 4 * g + 2 * hi;
        po[dp0 * 128 + qrel] = w0;
        po[(dp0 + 1) * 128 + qrel] = w1;
        po[(16 + dp0) * 128 + qrel] = w2;
        po[(16 + dp0 + 1) * 128 + qrel] = w3;
    }
    if (hi == 0) { pp[4096 + qrel] = m; pp[4224 + qrel] = lsum; }
}

// Combine strips of each (bh, q128-block).
__global__ __launch_bounds__(128) void merge_kernel(
    const float* __restrict__ part, float* __restrict__ out) {
    __shared__ float sc[6][128];
    int bid = blockIdx.x;          // 512 = 16 i x 32 bh
    int bh = bid & 31, i = bid >> 5;
    int n = (2 * i + 7) / 6;
    int sb = 0;
    for (int ii = 15; ii > i; --ii) sb += (2 * ii + 7) / 6;
    int t = threadIdx.x;           // q = t

    float mv[6], lv[6];
#pragma unroll
    for (int s2 = 0; s2 < 6; ++s2) {
        mv[s2] = -1e30f; lv[s2] = 0.f;
        if (s2 < n) {
            const float* pp = part + (size_t)((sb + s2) * 32 + bh) * PSTRIDE;
            mv[s2] = pp[4096 + t]; lv[s2] = pp[4224 + t];
        }
    }
    float nm = mv[0];
#pragma unroll
    for (int s2 = 1; s2 < 6; ++s2) nm = fmaxf(nm, mv[s2]);
    float den = 0.f;
    float cf[6];
#pragma unroll
    for (int s2 = 0; s2 < 6; ++s2) { cf[s2] = exp2f(mv[s2] - nm); den += lv[s2] * cf[s2]; }
    float inv = 1.0f / den;
#pragma unroll
    for (int s2 = 0; s2 < 6; ++s2) if (s2 < n) sc[s2][t] = cf[s2] * inv;
    __syncthreads();

    size_t obase = (size_t)bh * TL * 64 + (size_t)(128 * i + t) * 64;
    for (int seg = 0; seg < 4; ++seg) {
        float o[16];
#pragma unroll
        for (int j = 0; j < 16; ++j) o[j] = 0.f;
#pragma unroll
        for (int s2 = 0; s2 < 6; ++s2) {
            if (s2 < n) {
                const unsigned int* po =
                    (const unsigned int*)(part + (size_t)((sb + s2) * 32 + bh) * PSTRIDE);
                float wsc = sc[s2][t];
#pragma unroll
                for (int j = 0; j < 8; ++j) {
                    unsigned int wv = po[(seg * 8 + j) * 128 + t];
                    o[2 * j]     += wsc * __uint_as_float((wv & 0xffffu) << 16);
                    o[2 * j + 1] += wsc * __uint_as_float(wv & 0xffff0000u);
                }
            }
        }
#pragma unroll
        for (int c = 0; c < 4; ++c)
            *(f32x4*)(out + obase + seg * 16 + 4 * c) = *(const f32x4*)&o[4 * c];
    }
}

extern "C" void kernel_launch(void* const* d_in, const int* in_sizes, int n_in,
                              void* d_out, int out_size, void* d_ws, size_t ws_size,
                              hipStream_t stream) {
    const float* query = (const float*)d_in[0];
    const float* key = (const float*)d_in[1];
    const float* value = (const float*)d_in[2];
    const float* rel_pos_w = (const float*)d_in[5];
    const float* mlp_w = (const float*)d_in[8];
    float* out = (float*)d_out;

    unsigned short* Kb = (unsigned short*)d_ws;          // 8 MiB
    unsigned short* Vtb = Kb + 32 * 32 * 4096;           // 8 MiB
    float* rel_sf = (float*)(Vtb + 32 * 32 * 4096);      // 4*4096 f32
    float* vtbf = rel_sf + 4 * 4096;                     // 32768 f32
    float* part = vtbf + 32768;                          // 1632 * 4352 f32 ~ 28.4 MiB

    relscore_kernel<<<4095, 256, 0, stream>>>(rel_pos_w, mlp_w, rel_sf);
    preconv_kernel<<<1024, 256, 0, stream>>>(key, value, mlp_w, Kb, Vtb, vtbf);
    attn_kernel<<<1632, 256, 0, stream>>>(query, Kb, Vtb, rel_sf, vtbf, part);
    merge_kernel<<<512, 128, 0, stream>>>(part, out);
}

// Round 10
// 75.575 us; speedup vs baseline: 2.0277x; 2.0277x over previous
//
#include <hip/hip_runtime.h>

#define TL 2048
#define NHEAD 8
#define NLOC 4
#define L2E 1.44269504f
#define PSTRIDE 4352   // f32 per partial: 4096 (32dp x 128q u32 bf16x2) + 128 m + 128 l

typedef __attribute__((ext_vector_type(4))) float f32x4;
typedef __attribute__((ext_vector_type(16))) float f32x16;
typedef __attribute__((ext_vector_type(8))) __bf16 bf16x8;
typedef __attribute__((ext_vector_type(8))) unsigned short u16x8;
typedef __attribute__((ext_vector_type(4))) unsigned int u32x4;

static __device__ __forceinline__ unsigned short f2bf(float f) {
    unsigned u = __float_as_uint(f);
    u = (u + 0x7FFFu + ((u >> 16) & 1u)) >> 16;
    return (unsigned short)u;
}
static __device__ __forceinline__ unsigned int cvtpk(float a, float b) {
    unsigned int w;
    asm("v_cvt_pk_bf16_f32 %0, %1, %2" : "=v"(w) : "v"(a), "v"(b));
    return w;
}
static __device__ __forceinline__ void gl_lds16(const void* g, void* l) {
    __builtin_amdgcn_global_load_lds(
        (const __attribute__((address_space(1))) void*)g,
        (__attribute__((address_space(3))) void*)l, 16, 0, 0);
}

// blocks < 1024: K tile -> bf16 swizzled [64 k][8 d-chunks], V tile ->
//   bf16 transposed+swizzled [64 d][8 k-chunks]; chunk c of row r at c^(r&7).
//   Fused v_term f32 (local heads).
// blocks >= 1024: rel_scores[h', r] = dot(rel_pos_w[r,h'*64:+64], mlp_w[h'])*L2E
__global__ __launch_bounds__(256) void preconv_kernel(
    const float* __restrict__ key, const float* __restrict__ value,
    const float* __restrict__ mlp_w, const float* __restrict__ rel_pos_w,
    unsigned short* __restrict__ Kb, unsigned short* __restrict__ Vtb,
    float* __restrict__ vtbf, float* __restrict__ rel_sf) {
    int blk = blockIdx.x;
    int t = threadIdx.x;
    int wave = t >> 6, lane = t & 63;

    if (blk >= 1024) {
        // ---- relscore: 4 r-values per block, one per wave ----
        int r = (blk - 1024) * 4 + wave;
        if (r < 2 * TL - 1) {
#pragma unroll
            for (int hp = 0; hp < 4; ++hp) {
                float v = rel_pos_w[r * 256 + hp * 64 + lane] * mlp_w[hp * 64 + lane];
#pragma unroll
                for (int off = 32; off; off >>= 1) v += __shfl_xor(v, off);
                if (lane == 0) rel_sf[hp * 4096 + r] = v * L2E;
            }
        }
        return;
    }

    __shared__ float Vf[64][66];
    int bh = blk >> 5, kt = blk & 31;
    int h = bh & 7, b = bh >> 3;
    size_t src = (size_t)blk * 4096;
    size_t dst = (size_t)blk * 4096;

#pragma unroll
    for (int i = 0; i < 2; ++i) {
        int ch = t + i * 256;
        int row = ch >> 3, c = ch & 7;
        const float* kp = key + src + row * 64 + c * 8;
        f32x4 a = *(const f32x4*)kp;
        f32x4 bb = *(const f32x4*)(kp + 4);
        u16x8 o;
#pragma unroll
        for (int j = 0; j < 4; ++j) { o[j] = f2bf(a[j]); o[4 + j] = f2bf(bb[j]); }
        *(u16x8*)&Kb[dst + row * 64 + ((c ^ (row & 7)) << 3)] = o;
    }
    {
        int row = t >> 2, q4 = t & 3;
        const float* vp = value + src + row * 64 + q4 * 16;
#pragma unroll
        for (int j = 0; j < 4; ++j)
            *(f32x4*)&Vf[row][q4 * 16 + j * 4] = *(const f32x4*)(vp + j * 4);
    }
    __syncthreads();
#pragma unroll
    for (int i = 0; i < 2; ++i) {
        int ch = t + i * 256;
        int dr = ch >> 3, c = ch & 7;
        u16x8 o;
#pragma unroll
        for (int j = 0; j < 8; ++j) o[j] = f2bf(Vf[c * 8 + j][dr]);
        *(u16x8*)&Vtb[dst + dr * 64 + ((c ^ (dr & 7)) << 3)] = o;
    }
    if (h >= NLOC) {
        float mw = mlp_w[(h - NLOC) * 64 + lane];
        float* vout = vtbf + (size_t)((b * NLOC + h - NLOC) * TL) + kt * 64;
#pragma unroll
        for (int i = 0; i < 16; ++i) {
            int row = wave * 16 + i;
            float v = Vf[row][lane] * mw;
#pragma unroll
            for (int off = 32; off; off >>= 1) v += __shfl_xor(v, off);
            if (lane == 0) vout[row] = v * L2E;
        }
    }
}

#define MFMA32(A, B, C) __builtin_amdgcn_mfma_f32_32x32x16_bf16(A, B, C, 0, 0, 0)

// Flash attention, 32x32 MFMA, swapped QK^T, in-register P.
// 1 block = 4 waves x 32 q = 128 q-rows of one (bh, i), k-strip of <=6 tiles.
// Sequential 32-k subtiles (one live S f32x16 -> fits register budget).
// P half-exchange via v_permlane32_swap_b32 (pure VALU, no shfl/bpermute).
// All blocks write unnormalized partials (bf16 O^T + m + l); merge combines.
__global__ __launch_bounds__(256, 4) void attn_kernel(
    const float* __restrict__ query,
    const unsigned short* __restrict__ Kb, const unsigned short* __restrict__ Vtb,
    const float* __restrict__ rel_sf, const float* __restrict__ vtbf,
    float* __restrict__ part) {

    __shared__ __align__(16) unsigned char smem[35328];
    unsigned short* Ks0 = (unsigned short*)smem;            // [2][4096] u16
    unsigned short* Vt0 = (unsigned short*)(smem + 16384);  // [2][4096] u16
    float* relw  = (float*)(smem + 32768);                  // [512] f32 window
    float* biasf = (float*)(smem + 34816);                  // [2][64] f32

    int bid = blockIdx.x;          // 1632 = 51 sids x 32 bh, heavy sids first
    int bh = bid & 31;
    int sid = bid >> 5;
    // sid -> (i, s): i = 15..0, ns(i) = ceil((2i+2)/6) strips each
    int i = 0, s = 0, acc = 0;
#pragma unroll
    for (int ii = 15; ii >= 0; --ii) {
        int ns = (2 * ii + 7) / 6;
        if (sid >= acc && sid < acc + ns) { i = ii; s = sid - acc; }
        acc += ns;
    }
    int k_b = 6 * s;
    int k_e = min(6 * s + 6, 2 * i + 2);
    int q0 = i << 7;

    int h = bh & 7, b = bh >> 3;
    bool islocal = (h >= NLOC);
    int t = threadIdx.x;
    int w = t >> 6;
    int l31 = t & 31;
    int hi = (t >> 5) & 1;
    int sw = l31 & 7;
    int qrel = 32 * w + l31;
    int qglob = q0 + qrel;
    int qmaxw = q0 + 32 * w + 31;

    size_t tbase = (size_t)bh * 32 * 4096;
    const unsigned short* Ktiles = Kb + tbase;
    const unsigned short* Vtiles = Vtb + tbase;
    const float* vtpf = vtbf + (islocal ? (size_t)((b * NLOC + h - NLOC) * TL) : 0);
    int idxlo = 64 * k_b - q0 + 1920;                  // multiple of 64, >= 0
    const float* relsrc = rel_sf + (islocal ? ((h - NLOC) * 4096 + idxlo) : 0);

    // ---- prologue: stage tile k_b (async), rel window (512 f32), bias[0] ----
    gl_lds16(Ktiles + (size_t)k_b * 4096 + t * 8, Ks0 + t * 8);
    gl_lds16(Ktiles + (size_t)k_b * 4096 + 2048 + t * 8, Ks0 + 2048 + t * 8);
    gl_lds16(Vtiles + (size_t)k_b * 4096 + t * 8, Vt0 + t * 8);
    gl_lds16(Vtiles + (size_t)k_b * 4096 + 2048 + t * 8, Vt0 + 2048 + t * 8);
    if (islocal) {
        if (t < 128) *((f32x4*)relw + t) = *((const f32x4*)relsrc + t);
        if (t < 16) ((f32x4*)biasf)[t] = ((const f32x4*)(vtpf + (size_t)k_b * 64))[t];
    }

    // Q fragments (B-operand): col q = lane&31, d = 16*mq + 8*hi + e
    const float SC = 0.125f * L2E;
    bf16x8 qf[4];
    {
        const float* qsrc = query + ((size_t)bh * TL + qglob) * 64 + 8 * hi;
#pragma unroll
        for (int mq = 0; mq < 4; ++mq) {
            f32x4 a = *(const f32x4*)(qsrc + 16 * mq);
            f32x4 c = *(const f32x4*)(qsrc + 16 * mq + 4);
            u16x8 u;
#pragma unroll
            for (int j = 0; j < 4; ++j) { u[j] = f2bf(a[j] * SC); u[4 + j] = f2bf(c[j] * SC); }
            qf[mq] = __builtin_bit_cast(bf16x8, u);
        }
    }

    float m = -1e30f, lsum = 0.f;
    f32x16 O0 = {0,0,0,0,0,0,0,0,0,0,0,0,0,0,0,0};
    f32x16 O1 = {0,0,0,0,0,0,0,0,0,0,0,0,0,0,0,0};

    __syncthreads();

    int cur = 0;
    for (int kt = k_b; kt < k_e; ++kt) {
        unsigned short* Ks = Ks0 + cur * 4096;
        unsigned short* Vt = Vt0 + cur * 4096;
        const float* bias = biasf + cur * 64;

        if (kt + 1 < k_e) {
            int nb = cur ^ 1;
            gl_lds16(Ktiles + (size_t)(kt + 1) * 4096 + t * 8, Ks0 + nb * 4096 + t * 8);
            gl_lds16(Ktiles + (size_t)(kt + 1) * 4096 + 2048 + t * 8, Ks0 + nb * 4096 + 2048 + t * 8);
            gl_lds16(Vtiles + (size_t)(kt + 1) * 4096 + t * 8, Vt0 + nb * 4096 + t * 8);
            gl_lds16(Vtiles + (size_t)(kt + 1) * 4096 + 2048 + t * 8, Vt0 + nb * 4096 + 2048 + t * 8);
            if (islocal && t < 16)
                ((f32x4*)(biasf + nb * 64))[t] =
                    ((const f32x4*)(vtpf + (size_t)(kt + 1) * 64))[t];
        }

        bool active = (64 * kt <= qmaxw);           // wave-uniform
        bool maskt = (64 * kt + 63 > q0 + 32 * w);  // tile crosses diagonal
        if (active) {
#pragma unroll
            for (int h2 = 0; h2 < 2; ++h2) {
                // ---- S^T = mfma(K, Q) for 32-k subtile h2 ----
                f32x16 S = {0,0,0,0,0,0,0,0,0,0,0,0,0,0,0,0};
                __builtin_amdgcn_s_setprio(1);
#pragma unroll
                for (int mq = 0; mq < 4; ++mq) {
                    int ch = ((2 * mq + hi) ^ sw) << 3;
                    const bf16x8 kf = *(const bf16x8*)&Ks[(32 * h2 + l31) * 64 + ch];
                    S = MFMA32(kf, qf[mq], S);
                }
                __builtin_amdgcn_s_setprio(0);
                // lane: q = qglob; k = 64kt + 32h2 + (r&3) + 8(r>>2) + 4hi

                if (islocal) {
                    int rbase = 64 * (kt - k_b) + 32 * h2 + 4 * hi + 127 - qrel;
#pragma unroll
                    for (int g = 0; g < 4; ++g) {
                        int kk0 = 32 * h2 + 8 * g + 4 * hi;
                        f32x4 bv = *(const f32x4*)&bias[kk0];
#pragma unroll
                        for (int j = 0; j < 4; ++j)
                            S[4 * g + j] += bv[j] + relw[rbase + 8 * g + j];
                    }
                }
                if (maskt) {
                    int koff = 64 * kt + 32 * h2 + 4 * hi - qglob;
#pragma unroll
                    for (int r = 0; r < 16; ++r) {
                        int kk = (r & 3) + 8 * (r >> 2);
                        if (koff + kk > 0) S[r] = -1e30f;
                    }
                }
                // ---- online softmax (exp2 domain), defer-max ----
                float pmax = -1e30f;
#pragma unroll
                for (int r = 0; r < 16; ++r) pmax = fmaxf(pmax, S[r]);
                pmax = fmaxf(pmax, __shfl_xor(pmax, 32));
                if (__any(pmax > m + 11.5f)) {
                    float nm2 = fmaxf(m, pmax);
                    float corr = exp2f(m - nm2);
                    lsum *= corr;
#pragma unroll
                    for (int r = 0; r < 16; ++r) { O0[r] *= corr; O1[r] *= corr; }
                    m = nm2;
                }
                float ps = 0.f;
#pragma unroll
                for (int r = 0; r < 16; ++r) {
                    float p = exp2f(S[r] - m);
                    S[r] = p; ps += p;
                }
                ps += __shfl_xor(ps, 32);
                lsum += ps;

                // ---- P -> bf16 frags via v_permlane32_swap_b32, PV ----
                __builtin_amdgcn_s_setprio(1);
#pragma unroll
                for (int kq = 0; kq < 2; ++kq) {
                    int ra = 8 * kq;
                    unsigned int x0 = cvtpk(S[ra + 0], S[ra + 1]);
                    unsigned int x1 = cvtpk(S[ra + 2], S[ra + 3]);
                    unsigned int y0 = cvtpk(S[ra + 4], S[ra + 5]);
                    unsigned int y1 = cvtpk(S[ra + 6], S[ra + 7]);
                    // swap: x = {x.lo, y.lo}, y = {x.hi, y.hi}
                    asm("v_permlane32_swap_b32 %0, %1" : "+v"(x0), "+v"(y0));
                    asm("v_permlane32_swap_b32 %0, %1" : "+v"(x1), "+v"(y1));
                    u32x4 fw;
                    fw[0] = x0; fw[1] = x1; fw[2] = y0; fw[3] = y1;
                    const bf16x8 pf = __builtin_bit_cast(bf16x8, fw);
                    int ch = ((4 * h2 + 2 * kq + hi) ^ sw) << 3;
                    const bf16x8 vf0 = *(const bf16x8*)&Vt[l31 * 64 + ch];
                    const bf16x8 vf1 = *(const bf16x8*)&Vt[(32 + l31) * 64 + ch];
                    O0 = MFMA32(vf0, pf, O0);
                    O1 = MFMA32(vf1, pf, O1);
                }
                __builtin_amdgcn_s_setprio(0);
            }
        }
        __syncthreads();   // next tile staged; everyone done with cur
        cur ^= 1;
    }

    // ---- partial dump: [dp 32][q 128] u32 (bf16 pair), then m, l ----
    float* pp = part + (size_t)bid * PSTRIDE;
    unsigned int* po = (unsigned int*)pp;
#pragma unroll
    for (int g = 0; g < 4; ++g) {
        unsigned int w0 = cvtpk(O0[4 * g + 0], O0[4 * g + 1]);
        unsigned int w1 = cvtpk(O0[4 * g + 2], O0[4 * g + 3]);
        unsigned int w2 = cvtpk(O1[4 * g + 0], O1[4 * g + 1]);
        unsigned int w3 = cvtpk(O1[4 * g + 2], O1[4 * g + 3]);
        int dp0 = 4 * g + 2 * hi;
        po[dp0 * 128 + qrel] = w0;
        po[(dp0 + 1) * 128 + qrel] = w1;
        po[(16 + dp0) * 128 + qrel] = w2;
        po[(16 + dp0 + 1) * 128 + qrel] = w3;
    }
    if (hi == 0) { pp[4096 + qrel] = m; pp[4224 + qrel] = lsum; }
}

// Combine strips of each (bh, q128-block).
__global__ __launch_bounds__(128) void merge_kernel(
    const float* __restrict__ part, float* __restrict__ out) {
    __shared__ float sc[6][128];
    int bid = blockIdx.x;          // 512 = 16 i x 32 bh
    int bh = bid & 31, i = bid >> 5;
    int n = (2 * i + 7) / 6;
    int sb = 0;
    for (int ii = 15; ii > i; --ii) sb += (2 * ii + 7) / 6;
    int t = threadIdx.x;           // q = t

    float mv[6], lv[6];
#pragma unroll
    for (int s2 = 0; s2 < 6; ++s2) {
        mv[s2] = -1e30f; lv[s2] = 0.f;
        if (s2 < n) {
            const float* pp = part + (size_t)((sb + s2) * 32 + bh) * PSTRIDE;
            mv[s2] = pp[4096 + t]; lv[s2] = pp[4224 + t];
        }
    }
    float nm = mv[0];
#pragma unroll
    for (int s2 = 1; s2 < 6; ++s2) nm = fmaxf(nm, mv[s2]);
    float den = 0.f;
    float cf[6];
#pragma unroll
    for (int s2 = 0; s2 < 6; ++s2) { cf[s2] = exp2f(mv[s2] - nm); den += lv[s2] * cf[s2]; }
    float inv = 1.0f / den;
#pragma unroll
    for (int s2 = 0; s2 < 6; ++s2) if (s2 < n) sc[s2][t] = cf[s2] * inv;
    __syncthreads();

    size_t obase = (size_t)bh * TL * 64 + (size_t)(128 * i + t) * 64;
    for (int seg = 0; seg < 4; ++seg) {
        float o[16];
#pragma unroll
        for (int j = 0; j < 16; ++j) o[j] = 0.f;
#pragma unroll
        for (int s2 = 0; s2 < 6; ++s2) {
            if (s2 < n) {
                const unsigned int* po =
                    (const unsigned int*)(part + (size_t)((sb + s2) * 32 + bh) * PSTRIDE);
                float wsc = sc[s2][t];
#pragma unroll
                for (int j = 0; j < 8; ++j) {
                    unsigned int wv = po[(seg * 8 + j) * 128 + t];
                    o[2 * j]     += wsc * __uint_as_float((wv & 0xffffu) << 16);
                    o[2 * j + 1] += wsc * __uint_as_float(wv & 0xffff0000u);
                }
            }
        }
#pragma unroll
        for (int c = 0; c < 4; ++c)
            *(f32x4*)(out + obase + seg * 16 + 4 * c) = *(const f32x4*)&o[4 * c];
    }
}

extern "C" void kernel_launch(void* const* d_in, const int* in_sizes, int n_in,
                              void* d_out, int out_size, void* d_ws, size_t ws_size,
                              hipStream_t stream) {
    const float* query = (const float*)d_in[0];
    const float* key = (const float*)d_in[1];
    const float* value = (const float*)d_in[2];
    const float* rel_pos_w = (const float*)d_in[5];
    const float* mlp_w = (const float*)d_in[8];
    float* out = (float*)d_out;

    unsigned short* Kb = (unsigned short*)d_ws;          // 8 MiB
    unsigned short* Vtb = Kb + 32 * 32 * 4096;           // 8 MiB
    float* rel_sf = (float*)(Vtb + 32 * 32 * 4096);      // 4*4096 f32
    float* vtbf = rel_sf + 4 * 4096;                     // 32768 f32
    float* part = vtbf + 32768;                          // 1632 * 4352 f32 ~ 28.4 MiB

    preconv_kernel<<<2048, 256, 0, stream>>>(key, value, mlp_w, rel_pos_w,
                                             Kb, Vtb, vtbf, rel_sf);
    attn_kernel<<<1632, 256, 0, stream>>>(query, Kb, Vtb, rel_sf, vtbf, part);
    merge_kernel<<<512, 128, 0, stream>>>(part, out);
}